// Round 14
// baseline (132.993 us; speedup 1.0000x reference)
//
#include <hip/hip_runtime.h>

#define CH 64
#define RPB 8
#define BLOCK (RPB * 64)

typedef short short8 __attribute__((ext_vector_type(8)));
typedef float f32x4 __attribute__((ext_vector_type(4)));
typedef unsigned short ushort8v __attribute__((ext_vector_type(8)));
typedef _Float16 half2v __attribute__((ext_vector_type(2)));

__device__ __forceinline__ unsigned short f2bf(float f) {
    unsigned u = __float_as_uint(f);
    u += 0x7fff + ((u >> 16) & 1);          // round-to-nearest-even
    return (unsigned short)(u >> 16);
}
__device__ __forceinline__ float bf2f(unsigned short h) {
    return __uint_as_float(((unsigned)h) << 16);
}
__device__ __forceinline__ unsigned pkh2(float a, float b) {
    union { half2v h; unsigned u; } cv;
    cv.h = half2v{(_Float16)a, (_Float16)b};
    return cv.u;
}
__device__ __forceinline__ half2v u2h2(unsigned u) {
    union { unsigned u; half2v h; } cv;
    cv.u = u;
    return cv.h;
}
// RNE f32 pair -> packed bf16 dword (lo = bf16(a), hi = bf16(b))
__device__ __forceinline__ unsigned cvtpk_bf16(float a, float b) {
    unsigned r;
    __asm__ volatile("v_cvt_pk_bf16_f32 %0, %1, %2" : "=v"(r) : "v"(a), "v"(b));
    return r;
}

// Kernel A: row_ptr[r] = first edge index e with edge_row[e] >= r  (r in [0, N])
__global__ __launch_bounds__(256) void build_row_ptr(
    const int* __restrict__ erow, int* __restrict__ rp, int N, int E)
{
    int r = blockIdx.x * 256 + threadIdx.x;
    if (r > N) return;
    int lo = 0, len = E;
    while (len > 0) {
        int half = len >> 1;
        int probe = lo + half;
        int v = erow[probe];
        if (v < r) { lo = probe + 1; len -= half + 1; }
        else { len = half; }
    }
    rp[r] = lo;
}

// Kernel A2: precompute W as bf16 hi/lo fragments in mfma_16x16x32 B-layout.
// (validated r8) ws layout: wf[((h*4+ks)*4+nt)*512 + lane*8 + j]
__global__ __launch_bounds__(256) void prep_wfrag(
    const float* __restrict__ W, unsigned short* __restrict__ wf)
{
    int tid = blockIdx.x * 256 + threadIdx.x;
    if (tid >= 2048) return;
    int lane = tid & 63;
    int nt = (tid >> 6) & 3;
    int ks = (tid >> 8) & 3;
    int h  = (tid >> 10) & 1;
    int n  = nt * 16 + (lane & 15);
    int g  = lane >> 4;
    ushort8v o;
    #pragma unroll
    for (int j = 0; j < 8; ++j) {
        int kk = ks * 32 + g * 8 + j;
        float w = (kk < 64) ? W[kk * 64 + n] : W[4096 + (kk - 64) * 64 + n];
        unsigned short hi = f2bf(w);
        o[j] = h ? f2bf(w - bf2f(hi)) : hi;
    }
    *(ushort8v*)(wf + (size_t)tid * 8) = o;
}

// Kernel A3: pack X as interleaved f16 pairs: Xp[i] = h(Xi)<<16 | h(Xr)
__global__ __launch_bounds__(256) void pack_x(
    const float* __restrict__ Xr, const float* __restrict__ Xi,
    unsigned* __restrict__ Xp, int total4)
{
    int i = blockIdx.x * 256 + threadIdx.x;
    if (i >= total4) return;
    float4 r  = ((const float4*)Xr)[i];
    float4 im = ((const float4*)Xi)[i];
    uint4 o;
    o.x = pkh2(r.x, im.x);
    o.y = pkh2(r.y, im.y);
    o.z = pkh2(r.z, im.z);
    o.w = pkh2(r.w, im.w);
    ((uint4*)Xp)[i] = o;
}

// ---- spmm machinery (r13 trunk, 4-deep MLP); PK: f16 gathers + LDS L + dot2 ----
#define ISSUE(BUF, SB)                                                      \
    do {                                                                    \
        _Pragma("unroll")                                                   \
        for (int j_ = 0; j_ < 8; ++j_) {                                    \
            int c_ = __builtin_amdgcn_readlane(vcol, (SB) * 8 + j_);        \
            if constexpr (PK) {                                             \
                xp##BUF[j_] = Xp[(((unsigned)c_ << 6) | (unsigned)lane)];   \
            } else {                                                        \
                xr##BUF[j_] = Xr[(size_t)c_ * CH + lane];                   \
                xi##BUF[j_] = Xi[(size_t)c_ * CH + lane];                   \
            }                                                               \
        }                                                                   \
        __builtin_amdgcn_sched_barrier(0);                                  \
    } while (0)

#define PROC(BUF, SB)                                                       \
    do {                                                                    \
        _Pragma("unroll")                                                   \
        for (int j_ = 0; j_ < 8; ++j_) {                                    \
            int k_ = (SB) * 8 + j_;                                         \
            if constexpr (PK) {                                             \
                uint4 lv_ = *(const uint4*)(Lrow + k_ * 4);  /* uniform addr -> b128 broadcast */ \
                half2v xv_ = u2h2(xp##BUF[j_]);                             \
                a0 = __builtin_amdgcn_fdot2(xv_, u2h2(lv_.x), a0, false);   \
                b0 = __builtin_amdgcn_fdot2(xv_, u2h2(lv_.y), b0, false);   \
                a1 = __builtin_amdgcn_fdot2(xv_, u2h2(lv_.z), a1, false);   \
                b1 = __builtin_amdgcn_fdot2(xv_, u2h2(lv_.w), b1, false);   \
            } else {                                                        \
                float l0r_ = __uint_as_float(__builtin_amdgcn_readlane(__float_as_uint(vl0r), k_)); \
                float l0i_ = __uint_as_float(__builtin_amdgcn_readlane(__float_as_uint(vl0i), k_)); \
                float l1r_ = __uint_as_float(__builtin_amdgcn_readlane(__float_as_uint(vl1r), k_)); \
                float l1i_ = __uint_as_float(__builtin_amdgcn_readlane(__float_as_uint(vl1i), k_)); \
                a0 += l0r_ * xr##BUF[j_] - l0i_ * xi##BUF[j_];              \
                b0 += l0i_ * xr##BUF[j_] + l0r_ * xi##BUF[j_];              \
                a1 += l1r_ * xr##BUF[j_] - l1i_ * xi##BUF[j_];              \
                b1 += l1i_ * xr##BUF[j_] + l1r_ * xi##BUF[j_];              \
            }                                                               \
        }                                                                   \
    } while (0)

template<int NSB, bool PK>
__device__ __forceinline__ void proc_row(
    int vcol, const unsigned* __restrict__ Lrow,
    float vl0r, float vl0i, float vl1r, float vl1i,
    const unsigned* __restrict__ Xp,
    const float* __restrict__ Xr, const float* __restrict__ Xi, int lane,
    float& a0, float& b0, float& a1, float& b1)
{
    unsigned xpA[8], xpB[8], xpC[8], xpD[8];
    float xrA[8], xiA[8], xrB[8], xiB[8], xrC[8], xiC[8], xrD[8], xiD[8];
    // 4-deep: up to 32 gathers in flight before first consume
    ISSUE(A, 0);
    if constexpr (NSB > 1) ISSUE(B, 1);
    if constexpr (NSB > 2) ISSUE(C, 2);
    if constexpr (NSB > 3) ISSUE(D, 3);
    PROC(A, 0);
    if constexpr (NSB > 4) ISSUE(A, 4);
    if constexpr (NSB > 1) PROC(B, 1);
    if constexpr (NSB > 5) ISSUE(B, 5);
    if constexpr (NSB > 2) PROC(C, 2);
    if constexpr (NSB > 6) ISSUE(C, 6);
    if constexpr (NSB > 3) PROC(D, 3);
    if constexpr (NSB > 7) ISSUE(D, 7);
    if constexpr (NSB > 4) PROC(A, 4);
    if constexpr (NSB > 5) PROC(B, 5);
    if constexpr (NSB > 6) PROC(C, 6);
    if constexpr (NSB > 7) PROC(D, 7);
}

// Kernel B: r13 structure + 4-deep gather pipeline + cvt_pk epilogue.
template<bool PK>
__global__ __launch_bounds__(BLOCK, 6) void sdconv_fused(
    const unsigned* __restrict__ Xp,
    const float* __restrict__ Xr, const float* __restrict__ Xi,
    const float* __restrict__ Lr, const float* __restrict__ Li,
    const float* __restrict__ bias,
    const int* __restrict__ ecol, const int* __restrict__ rp,
    const unsigned short* __restrict__ wf,
    float* __restrict__ outR, float* __restrict__ outI,
    int N, int E)
{
    // [arr(4)][blockrow(8)][68]: 0,1 = a0,a1 (real); 2,3 = b0,b1 (imag)
    __shared__ __align__(16) float sA[4 * RPB * 68];       // 8.7 KB
    __shared__ __align__(16) unsigned Lw[RPB][64][4];      // 8 KB packed L variants

    const int t    = threadIdx.x;
    const int wave = t >> 6;
    const int lane = t & 63;
    const int r0   = blockIdx.x * RPB;
    const int row  = r0 + wave;

    int start = 0, end = 0;
    if (row < N) { start = rp[row]; end = rp[row + 1]; }
    start = __builtin_amdgcn_readfirstlane(start);
    end   = __builtin_amdgcn_readfirstlane(end);

    const float* __restrict__ Lr1 = Lr + E;
    const float* __restrict__ Li1 = Li + E;
    const unsigned* __restrict__ Lrow = &Lw[wave][0][0];

    float a0 = 0.f, b0 = 0.f, a1 = 0.f, b1 = 0.f;

    for (int base = start; base < end; base += 64) {
        // one coalesced metadata round for up to 64 edges (lane j = edge j)
        int  eid  = base + lane;
        bool ok   = eid < end;
        int  eidc = ok ? eid : start;
        int   vcol = ecol[eidc];
        float vl0r = ok ? Lr[eidc]  : 0.f;
        float vl0i = ok ? Li[eidc]  : 0.f;
        float vl1r = ok ? Lr1[eidc] : 0.f;
        float vl1i = ok ? Li1[eidc] : 0.f;

        if constexpr (PK) {
            // stage packed L-pair variants for LDS broadcast in PROC
            *(uint4*)&Lw[wave][lane][0] = make_uint4(
                pkh2(vl0r, -vl0i),   // -> a0
                pkh2(vl0i,  vl0r),   // -> b0
                pkh2(vl1r, -vl1i),   // -> a1
                pkh2(vl1i,  vl1r));  // -> b1
            __asm__ volatile("s_waitcnt lgkmcnt(0)" ::: "memory");  // wave-local RAW fence
        }

        int m = end - base; if (m > 64) m = 64;   // wave-uniform
        int nsb = (m + 7) >> 3;                   // 1..8 sub-batches of 8
        switch (nsb) {
            case 1: proc_row<1, PK>(vcol, Lrow, vl0r, vl0i, vl1r, vl1i, Xp, Xr, Xi, lane, a0, b0, a1, b1); break;
            case 2: proc_row<2, PK>(vcol, Lrow, vl0r, vl0i, vl1r, vl1i, Xp, Xr, Xi, lane, a0, b0, a1, b1); break;
            case 3: proc_row<3, PK>(vcol, Lrow, vl0r, vl0i, vl1r, vl1i, Xp, Xr, Xi, lane, a0, b0, a1, b1); break;
            case 4: proc_row<4, PK>(vcol, Lrow, vl0r, vl0i, vl1r, vl1i, Xp, Xr, Xi, lane, a0, b0, a1, b1); break;
            case 5: proc_row<5, PK>(vcol, Lrow, vl0r, vl0i, vl1r, vl1i, Xp, Xr, Xi, lane, a0, b0, a1, b1); break;
            case 6: proc_row<6, PK>(vcol, Lrow, vl0r, vl0i, vl1r, vl1i, Xp, Xr, Xi, lane, a0, b0, a1, b1); break;
            case 7: proc_row<7, PK>(vcol, Lrow, vl0r, vl0i, vl1r, vl1i, Xp, Xr, Xi, lane, a0, b0, a1, b1); break;
            default: proc_row<8, PK>(vcol, Lrow, vl0r, vl0i, vl1r, vl1i, Xp, Xr, Xi, lane, a0, b0, a1, b1); break;
        }
    }

    sA[(0 * RPB + wave) * 68 + lane] = a0;
    sA[(1 * RPB + wave) * 68 + lane] = a1;
    sA[(2 * RPB + wave) * 68 + lane] = b0;
    sA[(3 * RPB + wave) * 68 + lane] = b1;
    __syncthreads();

    // Dual-chain MFMA epilogue (validated r8/r9/r10/r13): waves 0-3 real,
    // 4-7 imag. A at bf16-hi (built via v_cvt_pk_bf16_f32); B hi+lo split.
    const int nt    = wave & 3;
    const int abase = (wave < 4) ? 0 : 2;
    const int cidx  = lane & 15;
    const int g     = lane >> 4;
    const int ar    = lane & 15;

    union S8 { unsigned u[4]; short8 s; };

    f32x4 acc = {0.f, 0.f, 0.f, 0.f};
    #pragma unroll
    for (int ks = 0; ks < 4; ++ks) {
        const int kk0 = ks * 32 + g * 8;
        S8 ah; ah.u[0] = 0; ah.u[1] = 0; ah.u[2] = 0; ah.u[3] = 0;
        if (ar < 8) {   // only validated A rows carry data
            const int arr = abase + (kk0 >= 64 ? 1 : 0);
            const float* src = &sA[(arr * RPB + ar) * 68 + (kk0 & 63)];
            float4 v0 = *(const float4*)src;
            float4 v1 = *(const float4*)(src + 4);
            ah.u[0] = cvtpk_bf16(v0.x, v0.y);
            ah.u[1] = cvtpk_bf16(v0.z, v0.w);
            ah.u[2] = cvtpk_bf16(v1.x, v1.y);
            ah.u[3] = cvtpk_bf16(v1.z, v1.w);
        }
        short8 bh = *(const short8*)(wf + (size_t)((0 * 4 + ks) * 4 + nt) * 512 + lane * 8);
        short8 bl = *(const short8*)(wf + (size_t)((1 * 4 + ks) * 4 + nt) * 512 + lane * 8);
        acc = __builtin_amdgcn_mfma_f32_16x16x32_bf16(ah.s, bh, acc, 0, 0, 0);
        acc = __builtin_amdgcn_mfma_f32_16x16x32_bf16(ah.s, bl, acc, 0, 0, 0);
    }

    // C/D: col=lane&15, row=(lane>>4)*4+q -> rows 0-7 live in lanes g<2
    if (g < 2) {
        float bv = bias[nt * 16 + cidx];
        float* dst = (wave < 4) ? outR : outI;
        #pragma unroll
        for (int q = 0; q < 4; ++q) {
            int grow = r0 + g * 4 + q;
            if (grow < N)
                dst[(size_t)grow * CH + nt * 16 + cidx] = acc[q] + bv;
        }
    }
}

extern "C" void kernel_launch(void* const* d_in, const int* in_sizes, int n_in,
                              void* d_out, int out_size, void* d_ws, size_t ws_size,
                              hipStream_t stream)
{
    const float* Xr   = (const float*)d_in[0];
    const float* Xi   = (const float*)d_in[1];
    const float* Lr   = (const float*)d_in[2];
    const float* Li   = (const float*)d_in[3];
    const float* W    = (const float*)d_in[4];
    const float* bias = (const float*)d_in[5];
    const int*   erow = (const int*)d_in[6];
    const int*   ecol = (const int*)d_in[7];

    const int N = in_sizes[0] / CH;
    const int E = in_sizes[6];

    int* rp = (int*)d_ws;
    size_t woff = (((size_t)(N + 1) * 4) + 255) & ~(size_t)255;
    unsigned short* wfrag = (unsigned short*)((char*)d_ws + woff);
    size_t xoff = (woff + 32 * 1024 + 255) & ~(size_t)255;
    unsigned* Xp = (unsigned*)((char*)d_ws + xoff);
    size_t need = xoff + (size_t)N * CH * 4;

    float* outR = (float*)d_out;
    float* outI = outR + (size_t)N * CH;

    hipLaunchKernelGGL(build_row_ptr, dim3((N + 1 + 255) / 256), dim3(256), 0, stream,
                       erow, rp, N, E);
    hipLaunchKernelGGL(prep_wfrag, dim3(8), dim3(256), 0, stream, W, wfrag);

    int nb = (N + RPB - 1) / RPB;
    if (ws_size >= need) {
        int total4 = N * CH / 4;
        hipLaunchKernelGGL(pack_x, dim3((total4 + 255) / 256), dim3(256), 0, stream,
                           Xr, Xi, Xp, total4);
        hipLaunchKernelGGL(sdconv_fused<true>, dim3(nb), dim3(BLOCK), 0, stream,
                           Xp, Xr, Xi, Lr, Li, bias, ecol, rp, wfrag, outR, outI, N, E);
    } else {
        hipLaunchKernelGGL(sdconv_fused<false>, dim3(nb), dim3(BLOCK), 0, stream,
                           (const unsigned*)nullptr, Xr, Xi, Lr, Li, bias, ecol, rp,
                           wfrag, outR, outI, N, E);
    }
}

// Round 15
// 121.100 us; speedup vs baseline: 1.0982x; 1.0982x over previous
//
#include <hip/hip_runtime.h>

#define CH 64
#define RPB 8
#define BLOCK (RPB * 64)

typedef short short8 __attribute__((ext_vector_type(8)));
typedef float f32x4 __attribute__((ext_vector_type(4)));
typedef unsigned short ushort8v __attribute__((ext_vector_type(8)));
typedef _Float16 half2v __attribute__((ext_vector_type(2)));

__device__ __forceinline__ unsigned short f2bf(float f) {
    unsigned u = __float_as_uint(f);
    u += 0x7fff + ((u >> 16) & 1);          // round-to-nearest-even
    return (unsigned short)(u >> 16);
}
__device__ __forceinline__ float bf2f(unsigned short h) {
    return __uint_as_float(((unsigned)h) << 16);
}
__device__ __forceinline__ unsigned pkh2(float a, float b) {
    union { half2v h; unsigned u; } cv;
    cv.h = half2v{(_Float16)a, (_Float16)b};
    return cv.u;
}
__device__ __forceinline__ half2v u2h2(unsigned u) {
    union { unsigned u; half2v h; } cv;
    cv.u = u;
    return cv.h;
}

// Kernel A: row_ptr[r] = first edge index e with edge_row[e] >= r  (r in [0, N])
__global__ __launch_bounds__(256) void build_row_ptr(
    const int* __restrict__ erow, int* __restrict__ rp, int N, int E)
{
    int r = blockIdx.x * 256 + threadIdx.x;
    if (r > N) return;
    int lo = 0, len = E;
    while (len > 0) {
        int half = len >> 1;
        int probe = lo + half;
        int v = erow[probe];
        if (v < r) { lo = probe + 1; len -= half + 1; }
        else { len = half; }
    }
    rp[r] = lo;
}

// Kernel A2: precompute W as bf16 hi/lo fragments in mfma_16x16x32 B-layout.
// (validated r8) ws layout: wf[((h*4+ks)*4+nt)*512 + lane*8 + j]
__global__ __launch_bounds__(256) void prep_wfrag(
    const float* __restrict__ W, unsigned short* __restrict__ wf)
{
    int tid = blockIdx.x * 256 + threadIdx.x;
    if (tid >= 2048) return;
    int lane = tid & 63;
    int nt = (tid >> 6) & 3;
    int ks = (tid >> 8) & 3;
    int h  = (tid >> 10) & 1;
    int n  = nt * 16 + (lane & 15);
    int g  = lane >> 4;
    ushort8v o;
    #pragma unroll
    for (int j = 0; j < 8; ++j) {
        int kk = ks * 32 + g * 8 + j;
        float w = (kk < 64) ? W[kk * 64 + n] : W[4096 + (kk - 64) * 64 + n];
        unsigned short hi = f2bf(w);
        o[j] = h ? f2bf(w - bf2f(hi)) : hi;
    }
    *(ushort8v*)(wf + (size_t)tid * 8) = o;
}

// Kernel A3: pack X as interleaved f16 pairs: Xp[i] = h(Xi)<<16 | h(Xr)
__global__ __launch_bounds__(256) void pack_x(
    const float* __restrict__ Xr, const float* __restrict__ Xi,
    unsigned* __restrict__ Xp, int total4)
{
    int i = blockIdx.x * 256 + threadIdx.x;
    if (i >= total4) return;
    float4 r  = ((const float4*)Xr)[i];
    float4 im = ((const float4*)Xi)[i];
    uint4 o;
    o.x = pkh2(r.x, im.x);
    o.y = pkh2(r.y, im.y);
    o.z = pkh2(r.z, im.z);
    o.w = pkh2(r.w, im.w);
    ((uint4*)Xp)[i] = o;
}

// ---- spmm machinery (r13 trunk). PK path: opaque asm gathers + counted
// s_waitcnt vmcnt(N) (compiler's auto-waitcnt can't see asm loads, so it
// cannot drain the pipeline early -- the r2/r14 re-serialization fix). ----
#define ISSUE(BUF, SB)                                                      \
    do {                                                                    \
        _Pragma("unroll")                                                   \
        for (int j_ = 0; j_ < 8; ++j_) {                                    \
            int c_ = __builtin_amdgcn_readlane(vcol, (SB) * 8 + j_);        \
            if constexpr (PK) {                                             \
                const unsigned* p_ =                                        \
                    Xp + (((unsigned)c_ << 6) | (unsigned)lane);            \
                asm volatile("global_load_dword %0, %1, off"                \
                             : "=v"(xp##BUF[j_]) : "v"(p_));                \
            } else {                                                        \
                xr##BUF[j_] = Xr[(size_t)c_ * CH + lane];                   \
                xi##BUF[j_] = Xi[(size_t)c_ * CH + lane];                   \
            }                                                               \
        }                                                                   \
        __builtin_amdgcn_sched_barrier(0);                                  \
    } while (0)

// Counted wait: ties the 8 loaded regs so no consumer can hoist above it.
#define WAIT_BUF(BUF, NSTR)                                                 \
    do {                                                                    \
        asm volatile("s_waitcnt vmcnt(" NSTR ")"                            \
                     : "+v"(xp##BUF[0]), "+v"(xp##BUF[1]),                  \
                       "+v"(xp##BUF[2]), "+v"(xp##BUF[3]),                  \
                       "+v"(xp##BUF[4]), "+v"(xp##BUF[5]),                  \
                       "+v"(xp##BUF[6]), "+v"(xp##BUF[7]));                 \
        __builtin_amdgcn_sched_barrier(0);                                  \
    } while (0)

#define PROC(BUF, SB)                                                       \
    do {                                                                    \
        _Pragma("unroll")                                                   \
        for (int j_ = 0; j_ < 8; ++j_) {                                    \
            int k_ = (SB) * 8 + j_;                                         \
            if constexpr (PK) {                                             \
                uint4 lv_ = *(const uint4*)(Lrow + k_ * 4);  /* uniform addr -> b128 broadcast */ \
                half2v xv_ = u2h2(xp##BUF[j_]);                             \
                a0 = __builtin_amdgcn_fdot2(xv_, u2h2(lv_.x), a0, false);   \
                b0 = __builtin_amdgcn_fdot2(xv_, u2h2(lv_.y), b0, false);   \
                a1 = __builtin_amdgcn_fdot2(xv_, u2h2(lv_.z), a1, false);   \
                b1 = __builtin_amdgcn_fdot2(xv_, u2h2(lv_.w), b1, false);   \
            } else {                                                        \
                float l0r_ = __uint_as_float(__builtin_amdgcn_readlane(__float_as_uint(vl0r), k_)); \
                float l0i_ = __uint_as_float(__builtin_amdgcn_readlane(__float_as_uint(vl0i), k_)); \
                float l1r_ = __uint_as_float(__builtin_amdgcn_readlane(__float_as_uint(vl1r), k_)); \
                float l1i_ = __uint_as_float(__builtin_amdgcn_readlane(__float_as_uint(vl1i), k_)); \
                a0 += l0r_ * xr##BUF[j_] - l0i_ * xi##BUF[j_];              \
                b0 += l0i_ * xr##BUF[j_] + l0r_ * xi##BUF[j_];              \
                a1 += l1r_ * xr##BUF[j_] - l1i_ * xi##BUF[j_];              \
                b1 += l1i_ * xr##BUF[j_] + l1r_ * xi##BUF[j_];              \
            }                                                               \
        }                                                                   \
    } while (0)

template<int NSB, bool PK>
__device__ __forceinline__ void proc_row(
    int vcol, const unsigned* __restrict__ Lrow,
    float vl0r, float vl0i, float vl1r, float vl1i,
    const unsigned* __restrict__ Xp,
    const float* __restrict__ Xr, const float* __restrict__ Xi, int lane,
    float& a0, float& b0, float& a1, float& b1)
{
    unsigned xpA[8], xpB[8];
    float xrA[8], xiA[8], xrB[8], xiB[8];
    if constexpr (PK) {
        // normalize the counter so stray compiler loads can't skew counts
        asm volatile("s_waitcnt vmcnt(0)");
        __builtin_amdgcn_sched_barrier(0);
        ISSUE(A, 0);
        if constexpr (NSB > 1) ISSUE(B, 1);
        if constexpr (NSB > 1) { WAIT_BUF(A, "8"); } else { WAIT_BUF(A, "0"); }
        PROC(A, 0);
        if constexpr (NSB > 2) ISSUE(A, 2);
        if constexpr (NSB > 1) {
            if constexpr (NSB > 2) { WAIT_BUF(B, "8"); } else { WAIT_BUF(B, "0"); }
            PROC(B, 1);
        }
        if constexpr (NSB > 3) ISSUE(B, 3);
        if constexpr (NSB > 2) {
            if constexpr (NSB > 3) { WAIT_BUF(A, "8"); } else { WAIT_BUF(A, "0"); }
            PROC(A, 2);
        }
        if constexpr (NSB > 4) ISSUE(A, 4);
        if constexpr (NSB > 3) {
            if constexpr (NSB > 4) { WAIT_BUF(B, "8"); } else { WAIT_BUF(B, "0"); }
            PROC(B, 3);
        }
        if constexpr (NSB > 5) ISSUE(B, 5);
        if constexpr (NSB > 4) {
            if constexpr (NSB > 5) { WAIT_BUF(A, "8"); } else { WAIT_BUF(A, "0"); }
            PROC(A, 4);
        }
        if constexpr (NSB > 6) ISSUE(A, 6);
        if constexpr (NSB > 5) {
            if constexpr (NSB > 6) { WAIT_BUF(B, "8"); } else { WAIT_BUF(B, "0"); }
            PROC(B, 5);
        }
        if constexpr (NSB > 7) ISSUE(B, 7);
        if constexpr (NSB > 6) {
            if constexpr (NSB > 7) { WAIT_BUF(A, "8"); } else { WAIT_BUF(A, "0"); }
            PROC(A, 6);
        }
        if constexpr (NSB > 7) { WAIT_BUF(B, "0"); PROC(B, 7); }
    } else {
        ISSUE(A, 0);
        if constexpr (NSB > 1) ISSUE(B, 1);
        PROC(A, 0);
        if constexpr (NSB > 2) ISSUE(A, 2);
        if constexpr (NSB > 1) PROC(B, 1);
        if constexpr (NSB > 3) ISSUE(B, 3);
        if constexpr (NSB > 2) PROC(A, 2);
        if constexpr (NSB > 4) ISSUE(A, 4);
        if constexpr (NSB > 3) PROC(B, 3);
        if constexpr (NSB > 5) ISSUE(B, 5);
        if constexpr (NSB > 4) PROC(A, 4);
        if constexpr (NSB > 6) ISSUE(A, 6);
        if constexpr (NSB > 5) PROC(B, 5);
        if constexpr (NSB > 7) ISSUE(B, 7);
        if constexpr (NSB > 6) PROC(A, 6);
        if constexpr (NSB > 7) PROC(B, 7);
    }
}

// Kernel B: r13 structure; PK path uses asm gathers + counted vmcnt pipeline.
template<bool PK>
__global__ __launch_bounds__(BLOCK, 6) void sdconv_fused(
    const unsigned* __restrict__ Xp,
    const float* __restrict__ Xr, const float* __restrict__ Xi,
    const float* __restrict__ Lr, const float* __restrict__ Li,
    const float* __restrict__ bias,
    const int* __restrict__ ecol, const int* __restrict__ rp,
    const unsigned short* __restrict__ wf,
    float* __restrict__ outR, float* __restrict__ outI,
    int N, int E)
{
    // [arr(4)][blockrow(8)][68]: 0,1 = a0,a1 (real); 2,3 = b0,b1 (imag)
    __shared__ __align__(16) float sA[4 * RPB * 68];       // 8.7 KB
    __shared__ __align__(16) unsigned Lw[RPB][64][4];      // 8 KB packed L variants

    const int t    = threadIdx.x;
    const int wave = t >> 6;
    const int lane = t & 63;
    const int r0   = blockIdx.x * RPB;
    const int row  = r0 + wave;

    int start = 0, end = 0;
    if (row < N) { start = rp[row]; end = rp[row + 1]; }
    start = __builtin_amdgcn_readfirstlane(start);
    end   = __builtin_amdgcn_readfirstlane(end);

    const float* __restrict__ Lr1 = Lr + E;
    const float* __restrict__ Li1 = Li + E;
    const unsigned* __restrict__ Lrow = &Lw[wave][0][0];

    float a0 = 0.f, b0 = 0.f, a1 = 0.f, b1 = 0.f;

    for (int base = start; base < end; base += 64) {
        // one coalesced metadata round for up to 64 edges (lane j = edge j)
        int  eid  = base + lane;
        bool ok   = eid < end;
        int  eidc = ok ? eid : start;
        int   vcol = ecol[eidc];
        float vl0r = ok ? Lr[eidc]  : 0.f;
        float vl0i = ok ? Li[eidc]  : 0.f;
        float vl1r = ok ? Lr1[eidc] : 0.f;
        float vl1i = ok ? Li1[eidc] : 0.f;

        if constexpr (PK) {
            // stage packed L-pair variants for LDS broadcast in PROC
            *(uint4*)&Lw[wave][lane][0] = make_uint4(
                pkh2(vl0r, -vl0i),   // -> a0
                pkh2(vl0i,  vl0r),   // -> b0
                pkh2(vl1r, -vl1i),   // -> a1
                pkh2(vl1i,  vl1r));  // -> b1
            __asm__ volatile("s_waitcnt lgkmcnt(0)" ::: "memory");  // wave-local RAW fence
        }

        int m = end - base; if (m > 64) m = 64;   // wave-uniform
        int nsb = (m + 7) >> 3;                   // 1..8 sub-batches of 8
        switch (nsb) {
            case 1: proc_row<1, PK>(vcol, Lrow, vl0r, vl0i, vl1r, vl1i, Xp, Xr, Xi, lane, a0, b0, a1, b1); break;
            case 2: proc_row<2, PK>(vcol, Lrow, vl0r, vl0i, vl1r, vl1i, Xp, Xr, Xi, lane, a0, b0, a1, b1); break;
            case 3: proc_row<3, PK>(vcol, Lrow, vl0r, vl0i, vl1r, vl1i, Xp, Xr, Xi, lane, a0, b0, a1, b1); break;
            case 4: proc_row<4, PK>(vcol, Lrow, vl0r, vl0i, vl1r, vl1i, Xp, Xr, Xi, lane, a0, b0, a1, b1); break;
            case 5: proc_row<5, PK>(vcol, Lrow, vl0r, vl0i, vl1r, vl1i, Xp, Xr, Xi, lane, a0, b0, a1, b1); break;
            case 6: proc_row<6, PK>(vcol, Lrow, vl0r, vl0i, vl1r, vl1i, Xp, Xr, Xi, lane, a0, b0, a1, b1); break;
            case 7: proc_row<7, PK>(vcol, Lrow, vl0r, vl0i, vl1r, vl1i, Xp, Xr, Xi, lane, a0, b0, a1, b1); break;
            default: proc_row<8, PK>(vcol, Lrow, vl0r, vl0i, vl1r, vl1i, Xp, Xr, Xi, lane, a0, b0, a1, b1); break;
        }
    }

    sA[(0 * RPB + wave) * 68 + lane] = a0;
    sA[(1 * RPB + wave) * 68 + lane] = a1;
    sA[(2 * RPB + wave) * 68 + lane] = b0;
    sA[(3 * RPB + wave) * 68 + lane] = b1;
    __syncthreads();

    // Dual-chain MFMA epilogue (validated r8/r9/r10/r13): waves 0-3 real,
    // 4-7 imag. A at bf16-hi; B keeps hi+lo split: Ah*(Bh+Bl).
    const int nt    = wave & 3;
    const int abase = (wave < 4) ? 0 : 2;
    const int cidx  = lane & 15;
    const int g     = lane >> 4;
    const int ar    = lane & 15;

    f32x4 acc = {0.f, 0.f, 0.f, 0.f};
    #pragma unroll
    for (int ks = 0; ks < 4; ++ks) {
        const int kk0 = ks * 32 + g * 8;
        short8 ah = {0, 0, 0, 0, 0, 0, 0, 0};
        if (ar < 8) {   // only validated A rows carry data
            const int arr = abase + (kk0 >= 64 ? 1 : 0);
            const float* src = &sA[(arr * RPB + ar) * 68 + (kk0 & 63)];
            float4 v0 = *(const float4*)src;
            float4 v1 = *(const float4*)(src + 4);
            float av[8] = {v0.x, v0.y, v0.z, v0.w, v1.x, v1.y, v1.z, v1.w};
            #pragma unroll
            for (int j = 0; j < 8; ++j)
                ah[j] = (short)f2bf(av[j]);
        }
        short8 bh = *(const short8*)(wf + (size_t)((0 * 4 + ks) * 4 + nt) * 512 + lane * 8);
        short8 bl = *(const short8*)(wf + (size_t)((1 * 4 + ks) * 4 + nt) * 512 + lane * 8);
        acc = __builtin_amdgcn_mfma_f32_16x16x32_bf16(ah, bh, acc, 0, 0, 0);
        acc = __builtin_amdgcn_mfma_f32_16x16x32_bf16(ah, bl, acc, 0, 0, 0);
    }

    // C/D: col=lane&15, row=(lane>>4)*4+q -> rows 0-7 live in lanes g<2
    if (g < 2) {
        float bv = bias[nt * 16 + cidx];
        float* dst = (wave < 4) ? outR : outI;
        #pragma unroll
        for (int q = 0; q < 4; ++q) {
            int grow = r0 + g * 4 + q;
            if (grow < N)
                dst[(size_t)grow * CH + nt * 16 + cidx] = acc[q] + bv;
        }
    }
}

extern "C" void kernel_launch(void* const* d_in, const int* in_sizes, int n_in,
                              void* d_out, int out_size, void* d_ws, size_t ws_size,
                              hipStream_t stream)
{
    const float* Xr   = (const float*)d_in[0];
    const float* Xi   = (const float*)d_in[1];
    const float* Lr   = (const float*)d_in[2];
    const float* Li   = (const float*)d_in[3];
    const float* W    = (const float*)d_in[4];
    const float* bias = (const float*)d_in[5];
    const int*   erow = (const int*)d_in[6];
    const int*   ecol = (const int*)d_in[7];

    const int N = in_sizes[0] / CH;
    const int E = in_sizes[6];

    int* rp = (int*)d_ws;
    size_t woff = (((size_t)(N + 1) * 4) + 255) & ~(size_t)255;
    unsigned short* wfrag = (unsigned short*)((char*)d_ws + woff);
    size_t xoff = (woff + 32 * 1024 + 255) & ~(size_t)255;
    unsigned* Xp = (unsigned*)((char*)d_ws + xoff);
    size_t need = xoff + (size_t)N * CH * 4;

    float* outR = (float*)d_out;
    float* outI = outR + (size_t)N * CH;

    hipLaunchKernelGGL(build_row_ptr, dim3((N + 1 + 255) / 256), dim3(256), 0, stream,
                       erow, rp, N, E);
    hipLaunchKernelGGL(prep_wfrag, dim3(8), dim3(256), 0, stream, W, wfrag);

    int nb = (N + RPB - 1) / RPB;
    if (ws_size >= need) {
        int total4 = N * CH / 4;
        hipLaunchKernelGGL(pack_x, dim3((total4 + 255) / 256), dim3(256), 0, stream,
                           Xr, Xi, Xp, total4);
        hipLaunchKernelGGL(sdconv_fused<true>, dim3(nb), dim3(BLOCK), 0, stream,
                           Xp, Xr, Xi, Lr, Li, bias, ecol, rp, wfrag, outR, outI, N, E);
    } else {
        hipLaunchKernelGGL(sdconv_fused<false>, dim3(nb), dim3(BLOCK), 0, stream,
                           (const unsigned*)nullptr, Xr, Xi, Lr, Li, bias, ecol, rp,
                           wfrag, outR, outI, N, E);
    }
}